// Round 4
// baseline (296.417 us; speedup 1.0000x reference)
//
#include <hip/hip_runtime.h>

typedef __attribute__((ext_vector_type(8))) short short8;
typedef __attribute__((ext_vector_type(4))) float f32x4;

#define XP_ELEMS (32u * 66u * 66u * 128u)  /* 17,842,176 bf16 elements */
#define WT_ELEMS (256u * 1152u)            /* 294,912 bf16 elements */
#define WS_NEED  ((size_t)(XP_ELEMS + WT_ELEMS) * 2u)

typedef const __attribute__((address_space(1))) void* gp1_t;
typedef __attribute__((address_space(3))) void* lp3_t;

__device__ __forceinline__ void gload16(const void* g, void* l) {
  __builtin_amdgcn_global_load_lds((gp1_t)g, (lp3_t)l, 16, 0, 0);
}

__device__ __forceinline__ short f2bf(float f) {
  unsigned u = __float_as_uint(f);
  u = (u + 0x7FFFu + ((u >> 16) & 1u)) >> 16;  // RNE truncate to bf16
  return (short)u;
}

// Fused prepass. Blocks 0..2047: transpose one (b,y) plane
// x[b][cin][y][px] fp32 -> x_p[b][y+1][px+1][cin] bf16 (halo zeroed).
// Blocks 2048..3199: weight[cout][cin][kh][kw] -> w_t[cout][kh][kw][cin] bf16.
__global__ __launch_bounds__(256) void prepass(const float* __restrict__ x,
                                               const float* __restrict__ wg,
                                               short* __restrict__ xp,
                                               short* __restrict__ wt) {
  __shared__ short lds[64 * 128];  // 16 KB
  const int t = threadIdx.x;
  if (blockIdx.x >= 2048) {
    int o    = (blockIdx.x - 2048) * 256 + t;  // < 294912 exactly
    int cout = o / 1152;
    int r    = o % 1152;
    int kh   = r / 384;
    int kw   = (r / 128) % 3;
    int cin  = r & 127;
    wt[o] = f2bf(wg[((cout * 128 + cin) * 3 + kh) * 3 + kw]);
    return;
  }
  const int y = blockIdx.x & 63;
  const int b = blockIdx.x >> 6;

  const float* src = x + (long)b * 128 * 4096 + y * 64;
#pragma unroll
  for (int i = 0; i < 8; ++i) {
    int f4 = t + i * 256;          // 0..2047
    int cin = f4 >> 4, px4 = f4 & 15;
    float4 v = *(const float4*)(src + (long)cin * 4096 + px4 * 4);
    float vv[4] = {v.x, v.y, v.z, v.w};
#pragma unroll
    for (int j = 0; j < 4; ++j) {
      int px = px4 * 4 + j;
      int g = (cin >> 3) ^ ((px ^ (px >> 2)) & 15);
      lds[px * 128 + (g << 3) + (cin & 7)] = f2bf(vv[j]);
    }
  }
  __syncthreads();
  short* dst = xp + ((long)(b * 66 + y + 1) * 66 + 1) * 128;
#pragma unroll
  for (int i = 0; i < 4; ++i) {
    int f8 = t + i * 256;          // 0..1023
    int px = f8 >> 4, c8 = f8 & 15;
    int g = c8 ^ ((px ^ (px >> 2)) & 15);
    short8 v = *(const short8*)&lds[px * 128 + (g << 3)];
    *(short8*)(dst + (long)px * 128 + c8 * 8) = v;
  }
  short8 z = (short8)0;
  short* rowbase = xp + (long)(b * 66 + y + 1) * 66 * 128;
  if (t < 32) {
    int px = (t < 16) ? 0 : 65;
    int c8 = t & 15;
    *(short8*)(rowbase + (long)px * 128 + c8 * 8) = z;
  }
  if (y == 0) {
    short* r0 = xp + (long)(b * 66) * 66 * 128;
    for (int idx = t; idx < 66 * 16; idx += 256) *(short8*)(r0 + idx * 8) = z;
  }
  if (y == 63) {
    short* r65 = xp + ((long)(b * 66) + 65) * 66 * 128;
    for (int idx = t; idx < 66 * 16; idx += 256) *(short8*)(r65 + idx * 8) = z;
  }
}

// Implicit-GEMM conv: C[m=cout][n=b*4096+y*64+x], 128m x 64n tile, BK=32,
// 4 waves x (64x32 = 4x2 of 16x16x32 bf16 MFMA). Small acc (32 AGPR) +
// launch_bounds(256,5) -> ~5 waves/SIMD to hide the barrier-drain latency
// (R3 evidence: structure is latency-bound, not issue- or barrier-count-bound).
__global__ __launch_bounds__(256, 5) void conv_gemm(const short* __restrict__ xp,
                                                    const short* __restrict__ wt,
                                                    float* __restrict__ out) {
  __shared__ short Alds[128 * 32];  // 8 KB
  __shared__ short Blds[64 * 32];   // 4 KB
  const int tid   = threadIdx.x;
  const int w     = tid >> 6;   // wave id 0..3 (uniform per wave)
  const int l     = tid & 63;
  const int l15   = l & 15;
  const int q     = l >> 4;
  const int ntile = blockIdx.x;       // 0..2047 (64-pixel n-tiles)
  const int m0    = blockIdx.y << 7;  // 0 or 128

  // staging: lane covers row = w*16 + (l>>2); LDS granule pos l&3 holds
  // source k-chunk (l&3)^swz(row), swz(row)=(row>>1)&3 (self-inverse).
  const int srow = (w << 4) + (l >> 2);
  const int sch8 = (((l & 3) ^ ((srow >> 1) & 3)) * 8);

  const long aoff0 = (long)(m0 + srow) * 1152 + sch8;
  const long aoff1 = aoff0 + (long)64 * 1152;  // rows +64: swz key unchanged (mod 4)

  long boff;
  {
    int ng = (ntile << 6) + srow;  // global n; tile never spans images
    int b = ng >> 12, yx = ng & 4095;
    int y = yx >> 6, xx = yx & 63;
    boff = ((long)(b * 66 + y) * 66 + xx) * 128 + sch8;
  }

  short* Adst0 = &Alds[(w << 4) * 32];
  short* Adst1 = Adst0 + 64 * 32;
  short* Bdst  = &Blds[(w << 4) * 32];

  f32x4 acc[4][2];
#pragma unroll
  for (int i = 0; i < 4; ++i)
#pragma unroll
    for (int j = 0; j < 2; ++j) acc[i][j] = (f32x4)0.f;

  const int wm = (w >> 1) << 6;  // wave's 64-row (m) offset in tile
  const int wn = (w & 1) << 5;   // wave's 32-col (n) offset in tile

#pragma unroll
  for (int khkw = 0; khkw < 9; ++khkw) {
    const int kh = khkw / 3, kw = khkw % 3;
    const long sB = (long)(kh * 66 + kw) * 128;  // uniform shift into x_p
    const int kkb = khkw << 7;
#pragma unroll
    for (int c4 = 0; c4 < 4; ++c4) {
      const int cin0 = c4 << 5;
      const int kk0  = kkb + cin0;
      gload16(wt + aoff0 + kk0, Adst0);
      gload16(wt + aoff1 + kk0, Adst1);
      gload16(xp + boff + sB + cin0, Bdst);
      __syncthreads();  // drains vmcnt -> staged data visible
      short8 af[4], bf[2];
#pragma unroll
      for (int i = 0; i < 4; ++i) {
        int rA = wm + (i << 4) + l15;
        af[i] = *(const short8*)&Alds[rA * 32 + ((q ^ ((rA >> 1) & 3)) << 3)];
      }
#pragma unroll
      for (int j = 0; j < 2; ++j) {
        int rB = wn + (j << 4) + l15;
        bf[j] = *(const short8*)&Blds[rB * 32 + ((q ^ ((rB >> 1) & 3)) << 3)];
      }
#pragma unroll
      for (int i = 0; i < 4; ++i)
#pragma unroll
        for (int j = 0; j < 2; ++j)
          acc[i][j] = __builtin_amdgcn_mfma_f32_16x16x32_bf16(af[i], bf[j],
                                                              acc[i][j], 0, 0, 0);
      __syncthreads();  // protect LDS before next stage overwrites
    }
  }

  // epilogue: C/D layout col=lane&15, row=quad*4+reg (m89/m91-verified)
  const int ngb = (ntile << 6) + wn;
  const int b   = ngb >> 12;
  const int yxb = ngb & 4095;
  float* outb = out + (long)b * (256 * 4096) + yxb + l15;
#pragma unroll
  for (int i = 0; i < 4; ++i) {
#pragma unroll
    for (int r = 0; r < 4; ++r) {
      const int cout = m0 + wm + (i << 4) + q * 4 + r;
      float* orow = outb + (long)cout * 4096;
#pragma unroll
      for (int j = 0; j < 2; ++j) orow[j * 16] = acc[i][j][r];
    }
  }
}

// Correctness fallback if workspace is too small (slow, fp32 direct conv).
__global__ __launch_bounds__(256) void naive_conv(const float* __restrict__ x,
                                                  const float* __restrict__ wgt,
                                                  float* __restrict__ out) {
  long o = (long)blockIdx.x * 256 + threadIdx.x;
  int xx = (int)(o & 63);
  int y  = (int)((o >> 6) & 63);
  int co = (int)((o >> 12) & 255);
  int b  = (int)(o >> 20);
  float s = 0.f;
  for (int ci = 0; ci < 128; ++ci) {
    for (int kh = 0; kh < 3; ++kh) {
      int iy = y + kh - 1;
      if (iy < 0 || iy > 63) continue;
      for (int kw = 0; kw < 3; ++kw) {
        int ix = xx + kw - 1;
        if (ix < 0 || ix > 63) continue;
        s += x[((long)(b * 128 + ci) * 64 + iy) * 64 + ix] *
             wgt[((co * 128 + ci) * 3 + kh) * 3 + kw];
      }
    }
  }
  out[o] = s;
}

extern "C" void kernel_launch(void* const* d_in, const int* in_sizes, int n_in,
                              void* d_out, int out_size, void* d_ws, size_t ws_size,
                              hipStream_t stream) {
  (void)in_sizes; (void)n_in;
  const float* x   = (const float*)d_in[0];
  const float* wgt = (const float*)d_in[1];
  float* out = (float*)d_out;
  if (ws_size >= WS_NEED) {
    short* xp = (short*)d_ws;
    short* wt = xp + XP_ELEMS;
    prepass<<<dim3(2048 + WT_ELEMS / 256), dim3(256), 0, stream>>>(x, wgt, xp, wt);
    conv_gemm<<<dim3(2048, 2), dim3(256), 0, stream>>>(xp, wt, out);
  } else {
    naive_conv<<<dim3(out_size / 256), dim3(256), 0, stream>>>(x, wgt, out);
  }
}